// Round 4
// baseline (305.935 us; speedup 1.0000x reference)
//
#include <hip/hip_runtime.h>
#include <hip/hip_bf16.h>

#define VN 50000
#define RN 5
#define AN 8
#define CN 32
#define KSTEPS 40   // RN*AN; one kstep == one (r,a), K=32 channels
#define NB 8        // N-blocks of 16 (NTOT = 128 = n_rot*T)

typedef __attribute__((ext_vector_type(8))) short bf16x8;
typedef __attribute__((ext_vector_type(4))) float f32x4;
typedef __attribute__((ext_vector_type(4))) int   i32x4;

__device__ __forceinline__ float b2f(short s) {
    union { unsigned u; float f; } cv;
    cv.u = ((unsigned)(unsigned short)s) << 16;
    return cv.f;
}
__device__ __forceinline__ short f2b(float f) {
    union { float f; unsigned u; } cv; cv.f = f;
    unsigned r = cv.u + 0x7fff + ((cv.u >> 16) & 1);   // RNE
    return (short)(r >> 16);
}

// f32 -> bf16 pack of the conv-1 input signal
__global__ void pack_x(const float* __restrict__ x, __hip_bfloat16* __restrict__ xb, int n4) {
    int i = blockIdx.x * blockDim.x + threadIdx.x;
    if (i >= n4) return;
    float4 v = ((const float4*)x)[i];
    ushort4 o;
    o.x = (unsigned short)f2b(v.x);
    o.y = (unsigned short)f2b(v.y);
    o.z = (unsigned short)f2b(v.z);
    o.w = (unsigned short)f2b(v.w);
    ((ushort4*)xb)[i] = o;
}

// Rolled templates -> MFMA-fragment-order bf16 matrices.
// Bp flat index = ((kstep*NB + nb)*64 + lane)*8 + j
// value = templ[t, r, (a - 2n) mod 8, c], k=(r*8+a)*32+c, nt=nb*16+(lane&15)
__global__ void build_Bp(const float* __restrict__ t1, const float* __restrict__ t2,
                         __hip_bfloat16* __restrict__ B1, __hip_bfloat16* __restrict__ B2) {
    int m = blockIdx.x * blockDim.x + threadIdx.x;
    if (m >= KSTEPS * NB * 64 * 8) return;
    int j = m & 7;
    int lane = (m >> 3) & 63;
    int nb = (m >> 9) & 7;
    int kstep = m >> 12;
    int c = ((lane >> 4) << 3) + j;
    int r = kstep >> 3, a = kstep & 7;
    int nt = nb * 16 + (lane & 15);
    int n = nt >> 5, t = nt & 31;
    int asrc = (a - 2 * n + 8) & 7;
    int src = ((t * RN + r) * AN + asrc) * CN + c;
    ((unsigned short*)B1)[m] = (unsigned short)f2b(t1[src]);
    ((unsigned short*)B2)[m] = (unsigned short)f2b(t2[src]);
}

// Fused gather + interp + GEMM + AngularMaxPool (+bias/residual/relu).
// 4 waves/block, each wave: 16 vertices x 128 (n,t). No LDS, no syncs.
template<bool FIRST>
__global__ __launch_bounds__(256, 3)
void conv_mfma(const __hip_bfloat16* __restrict__ xb,   // [V][32] bf16 input
               const int*   __restrict__ bc_idx,        // [V][120]
               const float* __restrict__ bc_w,          // [V][120]
               const __hip_bfloat16* __restrict__ Bp,   // fragment layout
               const float* __restrict__ bias,          // [32]
               const float* __restrict__ signal,        // residual f32 (conv2)
               __hip_bfloat16* __restrict__ out_bf,     // conv1 out (s1, bf16)
               float* __restrict__ out_f)               // conv2 out (f32)
{
    const int tid = threadIdx.x;
    const int wid = tid >> 6;
    const int lane = tid & 63;
    const int vbase = blockIdx.x * 64 + wid * 16;

    const int arow = lane & 15;          // A-fragment row = vertex within tile
    const int c0 = (lane >> 4) << 3;     // channel sub-offset (8 contiguous k)

    int v = vbase + arow;
    int vc = v < VN ? v : VN - 1;

    const i32x4* ipb = (const i32x4*)(bc_idx + vc * 120);   // 480B row, 16B aligned
    const f32x4* wpb = (const f32x4*)(bc_w  + vc * 120);
    const unsigned short* xs = (const unsigned short*)xb;
    const bf16x8* Bfrag = (const bf16x8*)Bp + lane;         // + (ks*NB+nb)*64

    f32x4 acc[NB];
#pragma unroll
    for (int nb = 0; nb < NB; ++nb) acc[nb] = (f32x4)(0.f);

    for (int r = 0; r < RN; ++r) {
        // wide preload of this r's 24 indices + 24 weights (registers, static idx)
        int I[24]; float W[24];
#pragma unroll
        for (int q = 0; q < 6; ++q) {
            i32x4 iv = __builtin_nontemporal_load(ipb + r * 6 + q);
            f32x4 wv = __builtin_nontemporal_load(wpb + r * 6 + q);
            I[q * 4 + 0] = iv[0]; I[q * 4 + 1] = iv[1];
            I[q * 4 + 2] = iv[2]; I[q * 4 + 3] = iv[3];
            W[q * 4 + 0] = wv[0]; W[q * 4 + 1] = wv[1];
            W[q * 4 + 2] = wv[2]; W[q * 4 + 3] = wv[3];
        }
#pragma unroll
        for (int a = 0; a < AN; ++a) {
            const int e = a * 3;
            int   i0 = I[e], i1 = I[e + 1], i2 = I[e + 2];
            float w0 = W[e], w1 = W[e + 1], w2 = W[e + 2];
            bf16x8 g0 = *(const bf16x8*)(xs + (size_t)i0 * CN + c0);
            bf16x8 g1 = *(const bf16x8*)(xs + (size_t)i1 * CN + c0);
            bf16x8 g2 = *(const bf16x8*)(xs + (size_t)i2 * CN + c0);
            bf16x8 af;
#pragma unroll
            for (int j = 0; j < 8; ++j) {
                float f = fmaf(w0, b2f(g0[j]), fmaf(w1, b2f(g1[j]), w2 * b2f(g2[j])));
                af[j] = f2b(f);
            }
            const int ks = r * AN + a;
#pragma unroll
            for (int nb = 0; nb < NB; ++nb) {
                bf16x8 bfr = Bfrag[(ks * NB + nb) * 64];
                acc[nb] = __builtin_amdgcn_mfma_f32_16x16x32_bf16(af, bfr, acc[nb], 0, 0, 0);
            }
        }
    }

    // Epilogue: AMP over n in-register (nt = nb*16+colD -> n=nb>>1, t-half=nb&1),
    // then bias (+residual) + relu + store.
    const int colD = lane & 15;
    const int rbase = (lane >> 4) << 2;
#pragma unroll
    for (int q = 0; q < 2; ++q) {
        f32x4 mx;
#pragma unroll
        for (int rg = 0; rg < 4; ++rg)
            mx[rg] = fmaxf(fmaxf(acc[q][rg], acc[q + 2][rg]),
                           fmaxf(acc[q + 4][rg], acc[q + 6][rg]));
        int t = q * 16 + colD;
        float b = bias[t];
#pragma unroll
        for (int rg = 0; rg < 4; ++rg) {
            int vv = vbase + rbase + rg;
            if (vv < VN) {
                float val = mx[rg] + b;
                if (FIRST) {
                    ((unsigned short*)out_bf)[vv * CN + t] =
                        (unsigned short)f2b(fmaxf(val, 0.f));   // reused -> keep in L2
                } else {
                    val += __builtin_nontemporal_load(signal + vv * CN + t);
                    __builtin_nontemporal_store(fmaxf(val, 0.f), out_f + vv * CN + t);
                }
            }
        }
    }
}

extern "C" void kernel_launch(void* const* d_in, const int* in_sizes, int n_in,
                              void* d_out, int out_size, void* d_ws, size_t ws_size,
                              hipStream_t stream) {
    const float* signal = (const float*)d_in[0];
    const int*   bc_idx = (const int*)d_in[1];
    const float* bc_w   = (const float*)d_in[2];
    const float* t1     = (const float*)d_in[3];
    const float* b1     = (const float*)d_in[4];
    const float* t2     = (const float*)d_in[5];
    const float* b2     = (const float*)d_in[6];
    float* out = (float*)d_out;

    __hip_bfloat16* ws = (__hip_bfloat16*)d_ws;
    __hip_bfloat16* xb  = ws;                       // V*32 bf16
    __hip_bfloat16* s1  = ws + VN * CN;             // V*32 bf16
    __hip_bfloat16* Bp1 = ws + 2 * VN * CN;         // 163840 bf16
    __hip_bfloat16* Bp2 = Bp1 + KSTEPS * NB * 64 * 8;
    // total ws use ~= 7.0 MB

    pack_x<<<(VN * CN / 4 + 255) / 256, 256, 0, stream>>>(signal, xb, VN * CN / 4);
    build_Bp<<<(KSTEPS * NB * 64 * 8) / 256, 256, 0, stream>>>(t1, t2, Bp1, Bp2);

    int blocks = (VN + 63) / 64;   // 4 waves/block, 16 v/wave
    conv_mfma<true ><<<blocks, 256, 0, stream>>>(xb, bc_idx, bc_w, Bp1, b1, nullptr, s1, nullptr);
    conv_mfma<false><<<blocks, 256, 0, stream>>>(s1, bc_idx, bc_w, Bp2, b2, signal, nullptr, out);
}

// Round 5
// 250.639 us; speedup vs baseline: 1.2206x; 1.2206x over previous
//
#include <hip/hip_runtime.h>
#include <hip/hip_bf16.h>

#define VN 50000
#define RN 5
#define AN 8
#define CN 32
#define KSTEPS 40   // RN*AN; one kstep == one (r,a), K=32 channels
#define NB 8        // N-blocks of 16 (NTOT = 128 = n_rot*T)

typedef __attribute__((ext_vector_type(8))) short bf16x8;
typedef __attribute__((ext_vector_type(4))) float f32x4;
typedef __attribute__((ext_vector_type(2))) float f32x2;
typedef __attribute__((ext_vector_type(2))) int   i32x2;

__device__ __forceinline__ float b2f(short s) {
    union { unsigned u; float f; } cv;
    cv.u = ((unsigned)(unsigned short)s) << 16;
    return cv.f;
}
__device__ __forceinline__ short f2b(float f) {
    union { float f; unsigned u; } cv; cv.f = f;
    unsigned r = cv.u + 0x7fff + ((cv.u >> 16) & 1);   // RNE
    return (short)(r >> 16);
}

// f32 -> bf16 pack of the conv-1 input signal
__global__ void pack_x(const float* __restrict__ x, __hip_bfloat16* __restrict__ xb, int n4) {
    int i = blockIdx.x * blockDim.x + threadIdx.x;
    if (i >= n4) return;
    float4 v = ((const float4*)x)[i];
    ushort4 o;
    o.x = (unsigned short)f2b(v.x);
    o.y = (unsigned short)f2b(v.y);
    o.z = (unsigned short)f2b(v.z);
    o.w = (unsigned short)f2b(v.w);
    ((ushort4*)xb)[i] = o;
}

// Rolled templates -> MFMA-fragment-order bf16 matrices.
// Bp flat index = ((kstep*NB + nb)*64 + lane)*8 + j
// value = templ[t, r, (a - 2n) mod 8, c], k=(r*8+a)*32+c, nt=nb*16+(lane&15)
__global__ void build_Bp(const float* __restrict__ t1, const float* __restrict__ t2,
                         __hip_bfloat16* __restrict__ B1, __hip_bfloat16* __restrict__ B2) {
    int m = blockIdx.x * blockDim.x + threadIdx.x;
    if (m >= KSTEPS * NB * 64 * 8) return;
    int j = m & 7;
    int lane = (m >> 3) & 63;
    int nb = (m >> 9) & 7;
    int kstep = m >> 12;
    int c = ((lane >> 4) << 3) + j;
    int r = kstep >> 3, a = kstep & 7;
    int nt = nb * 16 + (lane & 15);
    int n = nt >> 5, t = nt & 31;
    int asrc = (a - 2 * n + 8) & 7;
    int src = ((t * RN + r) * AN + asrc) * CN + c;
    ((unsigned short*)B1)[m] = (unsigned short)f2b(t1[src]);
    ((unsigned short*)B2)[m] = (unsigned short)f2b(t2[src]);
}

// Fused gather + interp + GEMM + AngularMaxPool (+bias/residual/relu).
// 1 wave/block, wave: 32 vertices x 128 (n,t). Software-pipelined:
//   bc idx/w vector-loads 3 pairs ahead (HBM lat), gathers 2 a-steps ahead (L2 lat).
template<bool FIRST>
__global__ __launch_bounds__(64, 2)
void conv_mfma(const __hip_bfloat16* __restrict__ xb,   // [V][32] bf16 input
               const int*   __restrict__ bc_idx,        // [V][120]
               const float* __restrict__ bc_w,          // [V][120]
               const __hip_bfloat16* __restrict__ Bp,   // fragment layout
               const float* __restrict__ bias,          // [32]
               const float* __restrict__ signal,        // residual f32 (conv2)
               __hip_bfloat16* __restrict__ out_bf,     // conv1 out (s1, bf16)
               float* __restrict__ out_f)               // conv2 out (f32)
{
    const int lane = threadIdx.x;        // 64-thread block = 1 wave
    const int vbase = blockIdx.x * 32;
    const int arow = lane & 15;
    const int c0 = (lane >> 4) << 3;

    int v0 = vbase + arow;   int vc0 = v0 < VN ? v0 : VN - 1;
    int v1 = v0 + 16;        int vc1 = v1 < VN ? v1 : VN - 1;

    const int*   ip0 = bc_idx + (size_t)vc0 * 120;
    const int*   ip1 = bc_idx + (size_t)vc1 * 120;
    const float* wp0 = bc_w   + (size_t)vc0 * 120;
    const float* wp1 = bc_w   + (size_t)vc1 * 120;
    const unsigned short* xs = (const unsigned short*)xb;
    const bf16x8* Bfrag = (const bf16x8*)Bp + lane;     // + (ks*NB+nb)*64

    f32x4 acc[2][NB];
#pragma unroll
    for (int mi = 0; mi < 2; ++mi)
#pragma unroll
        for (int nb = 0; nb < NB; ++nb) acc[mi][nb] = (f32x4)(0.f);

    // Pipeline state (all statically indexed after full unroll -> registers).
    i32x2 I[3][6];    // [pair-slot][row*3+q], q covers int elems {2q,2q+1} of the pair
    f32x2 W[3][6];
    bf16x8 G[3][6];   // [a-slot][row*3+i]

    auto LOADIW = [&](int s, int p) {    // p = pair index 0..19 (r = p>>2, within-r pair = p&3)
        const int off = (p >> 2) * 24 + (p & 3) * 6;   // int offset in 120-elem row (8B aligned)
#pragma unroll
        for (int q = 0; q < 3; ++q) {
            I[s][q]     = __builtin_nontemporal_load((const i32x2*)(ip0 + off) + q);
            I[s][3 + q] = __builtin_nontemporal_load((const i32x2*)(ip1 + off) + q);
            W[s][q]     = __builtin_nontemporal_load((const f32x2*)(wp0 + off) + q);
            W[s][3 + q] = __builtin_nontemporal_load((const f32x2*)(wp1 + off) + q);
        }
    };
    auto ISSUEG = [&](int g, int t) {    // t = a-step 0..39, uses pair slot (t>>1)%3
        const int s = (t >> 1) % 3, h = t & 1;
#pragma unroll
        for (int row = 0; row < 2; ++row)
#pragma unroll
            for (int i = 0; i < 3; ++i) {
                const int e = 3 * h + i;
                int idx = I[s][row * 3 + (e >> 1)][e & 1];
                G[g][row * 3 + i] = *(const bf16x8*)(xs + (size_t)idx * CN + c0);
            }
    };
    auto CONSUME = [&](int g, int t) {
        const int s = (t >> 1) % 3, h = t & 1;
        bf16x8 af[2];
#pragma unroll
        for (int row = 0; row < 2; ++row) {
            float w[3];
#pragma unroll
            for (int i = 0; i < 3; ++i) {
                const int e = 3 * h + i;
                w[i] = W[s][row * 3 + (e >> 1)][e & 1];
            }
#pragma unroll
            for (int j = 0; j < 8; ++j) {
                float f = fmaf(w[0], b2f(G[g][row * 3 + 0][j]),
                         fmaf(w[1], b2f(G[g][row * 3 + 1][j]),
                               w[2] * b2f(G[g][row * 3 + 2][j])));
                af[row][j] = f2b(f);
            }
        }
#pragma unroll
        for (int nb = 0; nb < NB; ++nb) {
            bf16x8 bfr = Bfrag[(t * NB + nb) * 64];
            acc[0][nb] = __builtin_amdgcn_mfma_f32_16x16x32_bf16(af[0], bfr, acc[0][nb], 0, 0, 0);
            acc[1][nb] = __builtin_amdgcn_mfma_f32_16x16x32_bf16(af[1], bfr, acc[1][nb], 0, 0, 0);
        }
    };

    // Prologue: 3 pairs of idx/w in flight, 2 a-steps of gathers in flight.
    LOADIW(0, 0); LOADIW(1, 1); LOADIW(2, 2);
    ISSUEG(0, 0); ISSUEG(1, 1);
#pragma unroll
    for (int t = 0; t < KSTEPS; ++t) {
        if (t + 2 < KSTEPS) ISSUEG((t + 2) % 3, t + 2);
        CONSUME(t % 3, t);
        if ((t & 1) && ((t >> 1) + 3) < 20) LOADIW(((t >> 1) + 3) % 3, (t >> 1) + 3);
    }

    // Epilogue: AMP over n in-register (nt = nb*16+colD -> n=nb>>1, t-half=nb&1),
    // then bias (+residual) + relu + store.
    const int colD = lane & 15;
    const int rbase = (lane >> 4) << 2;
#pragma unroll
    for (int mi = 0; mi < 2; ++mi) {
#pragma unroll
        for (int q = 0; q < 2; ++q) {
            f32x4 mx;
#pragma unroll
            for (int rg = 0; rg < 4; ++rg)
                mx[rg] = fmaxf(fmaxf(acc[mi][q][rg], acc[mi][q + 2][rg]),
                               fmaxf(acc[mi][q + 4][rg], acc[mi][q + 6][rg]));
            int t = q * 16 + colD;
            float b = bias[t];
#pragma unroll
            for (int rg = 0; rg < 4; ++rg) {
                int vv = vbase + mi * 16 + rbase + rg;
                if (vv < VN) {
                    float val = mx[rg] + b;
                    if (FIRST) {
                        ((unsigned short*)out_bf)[vv * CN + t] =
                            (unsigned short)f2b(fmaxf(val, 0.f));   // reused -> keep in L2
                    } else {
                        val += __builtin_nontemporal_load(signal + vv * CN + t);
                        __builtin_nontemporal_store(fmaxf(val, 0.f), out_f + vv * CN + t);
                    }
                }
            }
        }
    }
}

extern "C" void kernel_launch(void* const* d_in, const int* in_sizes, int n_in,
                              void* d_out, int out_size, void* d_ws, size_t ws_size,
                              hipStream_t stream) {
    const float* signal = (const float*)d_in[0];
    const int*   bc_idx = (const int*)d_in[1];
    const float* bc_w   = (const float*)d_in[2];
    const float* t1     = (const float*)d_in[3];
    const float* b1     = (const float*)d_in[4];
    const float* t2     = (const float*)d_in[5];
    const float* b2     = (const float*)d_in[6];
    float* out = (float*)d_out;

    __hip_bfloat16* ws = (__hip_bfloat16*)d_ws;
    __hip_bfloat16* xb  = ws;                       // V*32 bf16
    __hip_bfloat16* s1  = ws + VN * CN;             // V*32 bf16
    __hip_bfloat16* Bp1 = ws + 2 * VN * CN;         // 163840 bf16
    __hip_bfloat16* Bp2 = Bp1 + KSTEPS * NB * 64 * 8;
    // total ws use ~= 7.0 MB

    pack_x<<<(VN * CN / 4 + 255) / 256, 256, 0, stream>>>(signal, xb, VN * CN / 4);
    build_Bp<<<(KSTEPS * NB * 64 * 8) / 256, 256, 0, stream>>>(t1, t2, Bp1, Bp2);

    int blocks = (VN + 31) / 32;   // 1 wave/block, 32 v/wave
    conv_mfma<true ><<<blocks, 64, 0, stream>>>(xb, bc_idx, bc_w, Bp1, b1, nullptr, s1, nullptr);
    conv_mfma<false><<<blocks, 64, 0, stream>>>(s1, bc_idx, bc_w, Bp2, b2, signal, nullptr, out);
}